// Round 10
// baseline (88.872 us; speedup 1.0000x reference)
//
#include <hip/hip_runtime.h>

typedef unsigned short u16;
typedef unsigned int u32;
typedef __bf16 bf16x8 __attribute__((ext_vector_type(8)));
typedef float f32x4 __attribute__((ext_vector_type(4)));

// Prepped-weight layout in g_wbuf (bytes), rewritten fully by prep_kernel
// every launch (deterministic):
//   W1f @ 0      : 7kt*10nt*64lane*8elem u16 = 71680 B  (K 200->224, N 150->160, zero-padded)
//   W2f @ 71680  : 5kt*7nt*64lane*8elem u16  = 35840 B  (K 150->160, N 100->112, zero-padded)
//   b1p @ 107520 : 160 f32 (zero-padded)
//   b2p @ 108160 : 112 f32 (zero-padded)
#define W2F_OFF 71680
#define B1_OFF 107520
#define B2_OFF 108160
#define WS_BYTES 108608

__device__ __align__(256) unsigned char g_wbuf[WS_BYTES];

__device__ __forceinline__ u16 f2bf(float f) {
  __bf16 b = (__bf16)f;                    // hw RNE convert
  return __builtin_bit_cast(u16, b);
}
__device__ __forceinline__ u32 pk2bf(float a, float b) {
  return (u32)f2bf(a) | ((u32)f2bf(b) << 16);
}

__global__ void prep_kernel(const float* __restrict__ W1, const float* __restrict__ b1,
                            const float* __restrict__ W2, const float* __restrict__ b2)
{
  const int stride = gridDim.x * blockDim.x;
  const int tid0 = blockIdx.x * blockDim.x + threadIdx.x;
  u16* w1f = (u16*)g_wbuf;
  for (int e = tid0; e < 35840; e += stride) {
    int j = e & 7, l = (e >> 3) & 63, nt = (e >> 9) % 10, kt = e / 5120;
    int k = kt * 32 + ((l >> 4) << 3) + j;
    int n = nt * 16 + (l & 15);
    w1f[e] = (k < 200 && n < 150) ? f2bf(W1[k * 150 + n]) : (u16)0;
  }
  u16* w2f = (u16*)(g_wbuf + W2F_OFF);
  for (int e = tid0; e < 17920; e += stride) {
    int j = e & 7, l = (e >> 3) & 63, nt = (e >> 9) % 7, kt = e / 3584;
    int k = kt * 32 + ((l >> 4) << 3) + j;
    int n = nt * 16 + (l & 15);
    w2f[e] = (k < 150 && n < 100) ? f2bf(W2[k * 100 + n]) : (u16)0;
  }
  float* b1p = (float*)(g_wbuf + B1_OFF);
  for (int e = tid0; e < 160; e += stride) b1p[e] = (e < 150) ? b1[e] : 0.f;
  float* b2p = (float*)(g_wbuf + B2_OFF);
  for (int e = tid0; e < 112; e += stride) b2p[e] = (e < 100) ? b2[e] : 0.f;
}

// Frag-LDS staging helper: float4 chunk c (of 3200 for a 64-row tile) ->
// bf16 frag-major slot (XOR-swizzled) or compact k=192..199 region.
__device__ __forceinline__ void stage_write(u16* __restrict__ xs, int c, float4 v) {
  int row = c / 50, kc = c % 50;
  int k0 = kc * 4, mt = row >> 4;
  int idx;
  if (k0 < 192) {
    int F = mt * 6 + (k0 >> 5);
    int fl = (row & 15) | (((k0 & 31) >> 3) << 4);
    idx = (F * 64 + (fl ^ (F & 7))) * 8 + (k0 & 7);
  } else {
    idx = 12288 + mt * 128 + (row & 15) * 8 + (k0 - 192);
  }
  uint2 p;
  p.x = pk2bf(v.x, v.y);
  p.y = pk2bf(v.z, v.w);
  *reinterpret_cast<uint2*>(&xs[idx]) = p;
}

#define NT 8                    // 64-row tiles per block
#define SMEM_BYTES 159744       // 107520 (W) + 2*25600 (x dbuf) + 1024 (ps)

// 512 threads = 8 waves; wave wv: mt = wv>>1 (one 16-row m-tile), h = wv&1
// (n-half). W1f+W2f copied to LDS once per block -> all B-frag reads are
// conflict-free ds_read_b128 (no L2 latency chains). x double-buffered:
// issue tile t+1 loads early, write LDS after compute (T14), 3 barriers/tile.
__global__ __launch_bounds__(512, 2)
void fused_mlp(const float* __restrict__ x, float* __restrict__ out, int B)
{
  extern __shared__ __align__(16) u16 smem[];
  u16* wlds = smem;                          // 53760 u16: W1f [0,35840), W2f [35840,53760)
  float* ps = (float*)(smem + 79360);        // [2 phase][2 half][64 row]

  const int tid = threadIdx.x;
  const int lane = tid & 63;
  const int wv = tid >> 6;                   // 0..7
  const int h = wv & 1;
  const int mt = wv >> 1;                    // 0..3
  const int cl = lane & 15, gr = lane >> 4;

  // ---- copy prepped W (107520 B) into LDS, once per block ----
  {
    const uint4* src = (const uint4*)g_wbuf;
    uint4* dst = (uint4*)wlds;
    #pragma unroll
    for (int i = 0; i < 14; ++i) {
      int c = tid + i * 512;
      if (c < 6720) dst[c] = src[c];
    }
  }

  // tile-invariant biases
  const float* b1p = (const float*)(g_wbuf + B1_OFF);
  const float* b2p = (const float*)(g_wbuf + B2_OFF);
  float b1v[5];
  #pragma unroll
  for (int nt = 0; nt < 5; ++nt) b1v[nt] = b1p[(5 * h + nt) * 16 + cl];
  float b2v[4];
  #pragma unroll
  for (int nt = 0; nt < 4; ++nt)
    b2v[nt] = (nt < 3 || h == 0) ? b2p[(4 * h + nt) * 16 + cl] : 0.f;

  const long rowBase = (long)blockIdx.x * (NT * 64);
  const f32x4 zz = {0.f, 0.f, 0.f, 0.f};

  // ---- stage tile 0 ----
  float4 rv[7];
  {
    const float* xg = x + rowBase * 200;
    #pragma unroll
    for (int i = 0; i < 7; ++i) {
      int c = tid + i * 512;
      rv[i] = (c < 3200) ? *reinterpret_cast<const float4*>(xg + (c / 50) * 200 + (c % 50) * 4)
                         : make_float4(0.f, 0.f, 0.f, 0.f);
    }
    u16* x0 = smem + 53760;
    #pragma unroll
    for (int i = 0; i < 7; ++i) {
      int c = tid + i * 512;
      if (c < 3200) stage_write(x0, c, rv[i]);
    }
  }
  __syncthreads();   // W + tile0 staged

  for (int t = 0; t < NT; ++t) {
    u16* xcur = smem + 53760 + (t & 1) * 12800;
    u16* xnxt = smem + 53760 + ((t + 1) & 1) * 12800;
    const long r0t = rowBase + (long)t * 64;

    // issue next tile's global loads early (hide under compute)
    if (t + 1 < NT) {
      const float* xg = x + (r0t + 64) * 200;
      #pragma unroll
      for (int i = 0; i < 7; ++i) {
        int c = tid + i * 512;
        rv[i] = (c < 3200) ? *reinterpret_cast<const float4*>(xg + (c / 50) * 200 + (c % 50) * 4)
                           : make_float4(0.f, 0.f, 0.f, 0.f);
      }
    }

    // ---- GEMM1: [16 x 224] @ [224 x 80] per wave, B from LDS ----
    f32x4 acc1[5];
    #pragma unroll
    for (int nt = 0; nt < 5; ++nt) acc1[nt] = zz;

    #pragma unroll
    for (int kt = 0; kt < 7; ++kt) {
      bf16x8 a;
      if (kt < 6) {
        int F = mt * 6 + kt;
        a = *reinterpret_cast<const bf16x8*>(&xcur[(F * 64 + (lane ^ (F & 7))) * 8]);
      } else {
        union { bf16x8 v; u32 w[4]; } A;
        A.v = *reinterpret_cast<const bf16x8*>(&xcur[12288 + mt * 128 + cl * 8]);
        if (gr != 0) { A.w[0] = A.w[1] = A.w[2] = A.w[3] = 0u; }
        a = A.v;
      }
      #pragma unroll
      for (int nt = 0; nt < 5; ++nt) {
        bf16x8 b = *reinterpret_cast<const bf16x8*>(&wlds[((kt * 10 + 5 * h + nt) * 64 + lane) * 8]);
        acc1[nt] = __builtin_amdgcn_mfma_f32_16x16x32_bf16(a, b, acc1[nt], 0, 0, 0);
      }
    }
    __syncthreads();   // (B1) GEMM1 A-reads done before h1 overwrites xcur

    // ---- epilogue 1: bias + leaky, out1 partials, h1 -> xcur frags ----
    float rs[4] = {0, 0, 0, 0};
    #pragma unroll
    for (int nt = 0; nt < 5; ++nt) {
      int k2 = (5 * h + nt) * 16 + cl;      // h1 column = GEMM2 k index
      int kt2 = k2 >> 5;
      int l2base = 16 * ((k2 & 31) >> 3);
      int e2 = k2 & 7;
      #pragma unroll
      for (int j = 0; j < 4; ++j) {
        int l2 = gr * 4 + j + l2base;       // C/D: row=(lane>>4)*4+reg, col=lane&15
        float hv = acc1[nt][j] + b1v[nt];
        hv = (hv >= 0.f) ? hv : 0.1f * hv;
        rs[j] += hv;
        xcur[((mt * 5 + kt2) * 64 + l2) * 8 + e2] = f2bf(hv);
      }
    }
    #pragma unroll
    for (int j = 0; j < 4; ++j) {
      float s = rs[j];
      #pragma unroll
      for (int mask = 1; mask < 16; mask <<= 1) s += __shfl_xor(s, mask, 64);
      if (cl == 0) ps[h * 64 + mt * 16 + gr * 4 + j] = s;
    }
    __syncthreads();   // (B2) h1 frags + out1 partials visible

    if (tid < 64)
      out[r0t + tid] = (ps[tid] + ps[64 + tid]) * (1.f / 150.f);

    // ---- GEMM2: [16 x 160] @ [160 x 64/48] per wave, B from LDS ----
    f32x4 acc2[4];
    #pragma unroll
    for (int nt = 0; nt < 4; ++nt) acc2[nt] = zz;

    #pragma unroll
    for (int kt = 0; kt < 5; ++kt) {
      bf16x8 a = *reinterpret_cast<const bf16x8*>(&xcur[((mt * 5 + kt) * 64 + lane) * 8]);
      #pragma unroll
      for (int nt = 0; nt < 4; ++nt) {
        if (nt < 3 || h == 0) {
          bf16x8 b = *reinterpret_cast<const bf16x8*>(&wlds[35840 + ((kt * 7 + 4 * h + nt) * 64 + lane) * 8]);
          acc2[nt] = __builtin_amdgcn_mfma_f32_16x16x32_bf16(a, b, acc2[nt], 0, 0, 0);
        }
      }
    }

    // ---- epilogue 2: bias + leaky, out2 partials ----
    float ts[4] = {0, 0, 0, 0};
    #pragma unroll
    for (int nt = 0; nt < 4; ++nt) {
      if (nt < 3 || h == 0) {
        #pragma unroll
        for (int j = 0; j < 4; ++j) {
          float hv = acc2[nt][j] + b2v[nt];
          hv = (hv >= 0.f) ? hv : 0.1f * hv;
          ts[j] += hv;
        }
      }
    }
    #pragma unroll
    for (int j = 0; j < 4; ++j) {
      float s = ts[j];
      #pragma unroll
      for (int mask = 1; mask < 16; mask <<= 1) s += __shfl_xor(s, mask, 64);
      if (cl == 0) ps[128 + h * 64 + mt * 16 + gr * 4 + j] = s;
    }

    // write next tile's staged data (vmcnt drain happens at first rv use)
    if (t + 1 < NT) {
      #pragma unroll
      for (int i = 0; i < 7; ++i) {
        int c = tid + i * 512;
        if (c < 3200) stage_write(xnxt, c, rv[i]);
      }
    }
    __syncthreads();   // (B3) out2 partials + next tile staged

    if (tid < 64)
      out[B + r0t + tid] = (ps[128 + tid] + ps[192 + tid]) * (1.f / 100.f);
  }
}

extern "C" void kernel_launch(void* const* d_in, const int* in_sizes, int n_in,
                              void* d_out, int out_size, void* d_ws, size_t ws_size,
                              hipStream_t stream)
{
  const float* x  = (const float*)d_in[0];
  const float* W1 = (const float*)d_in[1];
  const float* b1 = (const float*)d_in[2];
  const float* W2 = (const float*)d_in[3];
  const float* b2 = (const float*)d_in[4];
  float* out = (float*)d_out;
  const int B = in_sizes[0] / 200;   // 262144

  hipFuncSetAttribute(reinterpret_cast<const void*>(fused_mlp),
                      hipFuncAttributeMaxDynamicSharedMemorySize, SMEM_BYTES);

  prep_kernel<<<64, 256, 0, stream>>>(W1, b1, W2, b2);
  fused_mlp<<<B / (NT * 64), 512, SMEM_BYTES, stream>>>(x, out, B);
}

// Round 11
// 77.970 us; speedup vs baseline: 1.1398x; 1.1398x over previous
//
#include <hip/hip_runtime.h>

typedef unsigned short u16;
typedef unsigned int u32;
typedef __bf16 bf16x8 __attribute__((ext_vector_type(8)));
typedef float f32x4 __attribute__((ext_vector_type(4)));

// Prepped-weight layout in g_wbuf (bytes), rewritten fully by prep_kernel
// every launch (deterministic):
//   W1f @ 0      : 7kt*10nt*64lane*8elem u16 = 71680 B  (K 200->224, N 150->160, zero-padded)
//   W2f @ 71680  : 5kt*7nt*64lane*8elem u16  = 35840 B  (K 150->160, N 100->112, zero-padded)
//   b1p @ 107520 : 160 f32 (zero-padded)
//   b2p @ 108160 : 112 f32 (zero-padded)
#define W2F_OFF 71680
#define B1_OFF 107520
#define B2_OFF 108160
#define WS_BYTES 108608

__device__ __align__(256) unsigned char g_wbuf[WS_BYTES];

__device__ __forceinline__ u16 f2bf(float f) {
  __bf16 b = (__bf16)f;                    // hw RNE convert
  return __builtin_bit_cast(u16, b);
}
__device__ __forceinline__ u32 pk2bf(float a, float b) {
  return (u32)f2bf(a) | ((u32)f2bf(b) << 16);  // fuses to v_cvt_pk_bf16_f32
}

__global__ void prep_kernel(const float* __restrict__ W1, const float* __restrict__ b1,
                            const float* __restrict__ W2, const float* __restrict__ b2)
{
  const int stride = gridDim.x * blockDim.x;
  const int tid0 = blockIdx.x * blockDim.x + threadIdx.x;
  u16* w1f = (u16*)g_wbuf;
  for (int e = tid0; e < 35840; e += stride) {
    int j = e & 7, l = (e >> 3) & 63, nt = (e >> 9) % 10, kt = e / 5120;
    int k = kt * 32 + ((l >> 4) << 3) + j;
    int n = nt * 16 + (l & 15);
    w1f[e] = (k < 200 && n < 150) ? f2bf(W1[k * 150 + n]) : (u16)0;
  }
  u16* w2f = (u16*)(g_wbuf + W2F_OFF);
  for (int e = tid0; e < 17920; e += stride) {
    int j = e & 7, l = (e >> 3) & 63, nt = (e >> 9) % 7, kt = e / 3584;
    int k = kt * 32 + ((l >> 4) << 3) + j;
    int n = nt * 16 + (l & 15);
    w2f[e] = (k < 150 && n < 100) ? f2bf(W2[k * 100 + n]) : (u16)0;
  }
  float* b1p = (float*)(g_wbuf + B1_OFF);
  for (int e = tid0; e < 160; e += stride) b1p[e] = (e < 150) ? b1[e] : 0.f;
  float* b2p = (float*)(g_wbuf + B2_OFF);
  for (int e = tid0; e < 112; e += stride) b2p[e] = (e < 100) ? b2[e] : 0.f;
}

// BM=64, 256 threads (4 waves). Wave (pr,h): pr = wv>>1 owns rows
// 32pr..32pr+31 (m-tiles 2pr,2pr+1), h = wv&1 owns the n-half.
// NO x staging: A-frags loaded straight from global (per kt the 4 lane-
// groups consume bytes 0..127 of one 128B line per row -> line-efficient),
// converted via pk-cvt in flight, with depth-1 prefetch on A (f32 regs)
// and B (bf16 regs). h1 handoff via per-pair LDS buffers. 2 barriers total.
// LDS 21504 B; (256,4) cap 128 regs (acc1 40 + look-ahead ~72 + addr fits).
__global__ __launch_bounds__(256, 4)
void fused_mlp(const float* __restrict__ x, float* __restrict__ out, int B)
{
  __shared__ __align__(16) u16 hbuf[2][5120];   // [pair][h1 frags: 2mt x 5kt x 64lane x 8]
  __shared__ float ps[2][2][64];                // [phase][half][block row]

  const int tid = threadIdx.x;
  const int lane = tid & 63;
  const int wv = tid >> 6;                  // 0..3
  const int h = wv & 1;
  const int pr = wv >> 1;
  const int cl = lane & 15, gr = lane >> 4;
  const long r0 = (long)blockIdx.x * 64;
  const long wr0 = r0 + pr * 32;

  const u16* w1g = (const u16*)g_wbuf;
  const u16* w2g = (const u16*)(g_wbuf + W2F_OFF);

  // per-lane global A bases: row wr0+cl (mt0) / +16 (mt1), k-offset gr*8
  const float* xb0 = x + (wr0 + cl) * 200 + gr * 8;
  const float* xb1 = xb0 + 16 * 200;

  // ---- preload kt=0: A in f32, B frags ----
  float4 cA0 = *reinterpret_cast<const float4*>(xb0);
  float4 cA1 = *reinterpret_cast<const float4*>(xb0 + 4);
  float4 cA2 = *reinterpret_cast<const float4*>(xb1);
  float4 cA3 = *reinterpret_cast<const float4*>(xb1 + 4);
  bf16x8 bfr[5];
  #pragma unroll
  for (int nt = 0; nt < 5; ++nt)
    bfr[nt] = *reinterpret_cast<const bf16x8*>(w1g + ((0 * 10 + 5 * h + nt) * 64 + lane) * 8);

  const f32x4 zz = {0.f, 0.f, 0.f, 0.f};
  f32x4 acc1[2][5];
  #pragma unroll
  for (int i = 0; i < 2; ++i)
    #pragma unroll
    for (int nt = 0; nt < 5; ++nt) acc1[i][nt] = zz;

  // ---- GEMM1: [32 x 224] @ [224 x 80] per wave; A+B depth-1 prefetch ----
  #pragma unroll
  for (int kt = 0; kt < 7; ++kt) {
    float4 nA0, nA1, nA2, nA3;
    bf16x8 bnx[5];
    if (kt < 6) {
      const int ko = (kt + 1) * 32;         // next kt's float offset
      if (kt + 1 < 6 || gr == 0) {          // kt==6 real only for gr==0 (k 192..199)
        nA0 = *reinterpret_cast<const float4*>(xb0 + ko);
        nA1 = *reinterpret_cast<const float4*>(xb0 + ko + 4);
        nA2 = *reinterpret_cast<const float4*>(xb1 + ko);
        nA3 = *reinterpret_cast<const float4*>(xb1 + ko + 4);
      } else {
        nA0 = nA1 = nA2 = nA3 = make_float4(0.f, 0.f, 0.f, 0.f);
      }
      #pragma unroll
      for (int nt = 0; nt < 5; ++nt)
        bnx[nt] = *reinterpret_cast<const bf16x8*>(w1g + (((kt + 1) * 10 + 5 * h + nt) * 64 + lane) * 8);
    }
    // convert current A f32 -> bf16 frags
    union { bf16x8 v; u32 w[4]; } A0, A1;
    A0.w[0] = pk2bf(cA0.x, cA0.y); A0.w[1] = pk2bf(cA0.z, cA0.w);
    A0.w[2] = pk2bf(cA1.x, cA1.y); A0.w[3] = pk2bf(cA1.z, cA1.w);
    A1.w[0] = pk2bf(cA2.x, cA2.y); A1.w[1] = pk2bf(cA2.z, cA2.w);
    A1.w[2] = pk2bf(cA3.x, cA3.y); A1.w[3] = pk2bf(cA3.z, cA3.w);
    #pragma unroll
    for (int nt = 0; nt < 5; ++nt) {
      acc1[0][nt] = __builtin_amdgcn_mfma_f32_16x16x32_bf16(A0.v, bfr[nt], acc1[0][nt], 0, 0, 0);
      acc1[1][nt] = __builtin_amdgcn_mfma_f32_16x16x32_bf16(A1.v, bfr[nt], acc1[1][nt], 0, 0, 0);
    }
    if (kt < 6) {
      cA0 = nA0; cA1 = nA1; cA2 = nA2; cA3 = nA3;
      #pragma unroll
      for (int nt = 0; nt < 5; ++nt) bfr[nt] = bnx[nt];
    }
  }

  // ---- epilogue 1: bias + leaky, out1 partials, h1 -> pair LDS frags ----
  const float* b1p = (const float*)(g_wbuf + B1_OFF);
  float b1v[5];
  #pragma unroll
  for (int nt = 0; nt < 5; ++nt) b1v[nt] = b1p[(5 * h + nt) * 16 + cl];

  float rs0[4] = {0, 0, 0, 0}, rs1[4] = {0, 0, 0, 0};
  #pragma unroll
  for (int nt = 0; nt < 5; ++nt) {
    int k2 = (5 * h + nt) * 16 + cl;        // h1 column = GEMM2 k index
    int kt2 = k2 >> 5;
    int l2base = 16 * ((k2 & 31) >> 3);
    int e2 = k2 & 7;
    #pragma unroll
    for (int j = 0; j < 4; ++j) {
      int l2 = gr * 4 + j + l2base;         // C/D: row=(lane>>4)*4+reg, col=lane&15
      float hv = acc1[0][nt][j] + b1v[nt];
      hv = (hv >= 0.f) ? hv : 0.1f * hv;
      rs0[j] += hv;
      hbuf[pr][(kt2 * 64 + l2) * 8 + e2] = f2bf(hv);          // local mt 0
      float gv = acc1[1][nt][j] + b1v[nt];
      gv = (gv >= 0.f) ? gv : 0.1f * gv;
      rs1[j] += gv;
      hbuf[pr][((5 + kt2) * 64 + l2) * 8 + e2] = f2bf(gv);    // local mt 1
    }
  }
  #pragma unroll
  for (int j = 0; j < 4; ++j) {
    float s0 = rs0[j], s1 = rs1[j];
    #pragma unroll
    for (int mask = 1; mask < 16; mask <<= 1) {
      s0 += __shfl_xor(s0, mask, 64);
      s1 += __shfl_xor(s1, mask, 64);
    }
    if (cl == 0) {
      ps[0][h][pr * 32 + gr * 4 + j]      = s0;
      ps[0][h][pr * 32 + 16 + gr * 4 + j] = s1;
    }
  }
  __syncthreads();   // (1) h1 frags + out1 partials visible

  if (tid < 64)
    out[r0 + tid] = (ps[0][0][tid] + ps[0][1][tid]) * (1.f / 150.f);

  // ---- GEMM2: [32 x 160] @ [160 x 64/48] per wave; B depth-1 prefetch ----
  f32x4 acc2[2][4];
  #pragma unroll
  for (int i = 0; i < 2; ++i)
    #pragma unroll
    for (int nt = 0; nt < 4; ++nt) acc2[i][nt] = zz;

  bf16x8 b2r[4];
  #pragma unroll
  for (int nt = 0; nt < 4; ++nt)
    if (nt < 3 || h == 0)
      b2r[nt] = *reinterpret_cast<const bf16x8*>(w2g + ((0 * 7 + 4 * h + nt) * 64 + lane) * 8);

  #pragma unroll
  for (int kt = 0; kt < 5; ++kt) {
    bf16x8 bnx2[4];
    if (kt < 4) {
      #pragma unroll
      for (int nt = 0; nt < 4; ++nt)
        if (nt < 3 || h == 0)
          bnx2[nt] = *reinterpret_cast<const bf16x8*>(w2g + (((kt + 1) * 7 + 4 * h + nt) * 64 + lane) * 8);
    }
    bf16x8 a0 = *reinterpret_cast<const bf16x8*>(&hbuf[pr][(kt * 64 + lane) * 8]);
    bf16x8 a1 = *reinterpret_cast<const bf16x8*>(&hbuf[pr][((5 + kt) * 64 + lane) * 8]);
    #pragma unroll
    for (int nt = 0; nt < 4; ++nt) {
      if (nt < 3 || h == 0) {
        acc2[0][nt] = __builtin_amdgcn_mfma_f32_16x16x32_bf16(a0, b2r[nt], acc2[0][nt], 0, 0, 0);
        acc2[1][nt] = __builtin_amdgcn_mfma_f32_16x16x32_bf16(a1, b2r[nt], acc2[1][nt], 0, 0, 0);
      }
    }
    if (kt < 4) {
      #pragma unroll
      for (int nt = 0; nt < 4; ++nt)
        if (nt < 3 || h == 0) b2r[nt] = bnx2[nt];
    }
  }

  // ---- epilogue 2: bias + leaky, out2 partials ----
  const float* b2p = (const float*)(g_wbuf + B2_OFF);
  float b2v[4];
  #pragma unroll
  for (int nt = 0; nt < 4; ++nt)
    b2v[nt] = (nt < 3 || h == 0) ? b2p[(4 * h + nt) * 16 + cl] : 0.f;

  float t0[4] = {0, 0, 0, 0}, t1[4] = {0, 0, 0, 0};
  #pragma unroll
  for (int nt = 0; nt < 4; ++nt) {
    if (nt < 3 || h == 0) {
      #pragma unroll
      for (int j = 0; j < 4; ++j) {
        float hv = acc2[0][nt][j] + b2v[nt];
        hv = (hv >= 0.f) ? hv : 0.1f * hv;
        t0[j] += hv;
        float gv = acc2[1][nt][j] + b2v[nt];
        gv = (gv >= 0.f) ? gv : 0.1f * gv;
        t1[j] += gv;
      }
    }
  }
  #pragma unroll
  for (int j = 0; j < 4; ++j) {
    float s0 = t0[j], s1 = t1[j];
    #pragma unroll
    for (int mask = 1; mask < 16; mask <<= 1) {
      s0 += __shfl_xor(s0, mask, 64);
      s1 += __shfl_xor(s1, mask, 64);
    }
    if (cl == 0) {
      ps[1][h][pr * 32 + gr * 4 + j]      = s0;
      ps[1][h][pr * 32 + 16 + gr * 4 + j] = s1;
    }
  }
  __syncthreads();   // (2) out2 partials visible

  if (tid < 64)
    out[B + r0 + tid] = (ps[1][0][tid] + ps[1][1][tid]) * (1.f / 100.f);
}

extern "C" void kernel_launch(void* const* d_in, const int* in_sizes, int n_in,
                              void* d_out, int out_size, void* d_ws, size_t ws_size,
                              hipStream_t stream)
{
  const float* x  = (const float*)d_in[0];
  const float* W1 = (const float*)d_in[1];
  const float* b1 = (const float*)d_in[2];
  const float* W2 = (const float*)d_in[3];
  const float* b2 = (const float*)d_in[4];
  float* out = (float*)d_out;
  const int B = in_sizes[0] / 200;   // 262144

  prep_kernel<<<64, 256, 0, stream>>>(W1, b1, W2, b2);
  fused_mlp<<<B / 64, 256, 0, stream>>>(x, out, B);
}